// Round 6
// baseline (4876.052 us; speedup 1.0000x reference)
//
#include <hip/hip_runtime.h>

// NewGRU: B=64, T=2048, D=256, U=256
// R5: scan = 4 waves x 64 cols (256 thr, 1 wave/SIMD, __launch_bounds__(256,1)):
//  - halves the redundant h/r B-fragment LDS reads (each wave reads the full
//    tile; 4 readers instead of 8)
//  - weights (384 dwords/thread) AGPR-resident via unified RF; MFMA reads A
//    from AGPR natively
//  - per-wave-private A' ring chunks, 6 global_load_lds/step, vmcnt(12) counted
//  - 4-deep unroll -> all ring slot offsets compile-time constants
//  - packed bf16->f32 unpack (shl/and), conflict-free 544B-stride h/r tiles

#define TT 2048
#define DD 256

typedef __attribute__((ext_vector_type(8))) short short8;          // 8 x bf16 bits
typedef __attribute__((ext_vector_type(4))) unsigned short us4;    // 4 x bf16 bits
typedef __attribute__((ext_vector_type(2))) unsigned int uint2v;   // 8B store
typedef __attribute__((ext_vector_type(4))) unsigned int uint4v;   // 16B load
typedef __attribute__((ext_vector_type(4))) float f32x4;

__device__ __forceinline__ unsigned short f2bf(float f) {          // RTN f32->bf16
  unsigned u = __float_as_uint(f);
  return (unsigned short)((u + 0x7FFFu + ((u >> 16) & 1u)) >> 16);
}
__device__ __forceinline__ float bflo(unsigned v) { return __uint_as_float(v << 16); }
__device__ __forceinline__ float bfhi(unsigned v) { return __uint_as_float(v & 0xFFFF0000u); }
__device__ __forceinline__ unsigned pk2(float lo, float hi) {      // 2xbf16 pack
  unsigned a = __float_as_uint(lo) + 0x8000u;
  unsigned b = __float_as_uint(hi) + 0x8000u;
  return (b & 0xFFFF0000u) | (a >> 16);
}
__device__ __forceinline__ float sigmoid_f(float x) {
  return __builtin_amdgcn_rcpf(1.f + __builtin_amdgcn_exp2f(x * -1.44269504f));
}
__device__ __forceinline__ float tanh_f(float x) {
  return 1.f - 2.f * __builtin_amdgcn_rcpf(1.f + __builtin_amdgcn_exp2f(x * 2.88539008f));
}
__device__ __forceinline__ f32x4 mfma16(short8 a, short8 b, f32x4 c) {
  return __builtin_amdgcn_mfma_f32_16x16x32_bf16(a, b, c, 0, 0, 0);
}
__device__ __forceinline__ void load_lds16(const void* gp, void* lp) {
  __builtin_amdgcn_global_load_lds((__attribute__((address_space(1))) void*)(gp),
                                   (__attribute__((address_space(3))) void*)(lp),
                                   16, 0, 0);
}
// XOR swizzle used only by proj_kernel's x tile (verified R1).
__device__ __forceinline__ unsigned swz(unsigned row, unsigned byteInRow) {
  return row * 512u + (byteInRow ^ ((row & 7u) << 4));
}

// ---------------------------------------------------------------------------
// proj_kernel: VERBATIM R4 (verified). Store layout: per (t,g,bblk) region,
// ct-pair p=ct>>1 occupies p*512 shorts, lane slot l*8 shorts (16B: even-ct us4
// | odd-ct us4).
// ---------------------------------------------------------------------------
__global__ __launch_bounds__(512) void proj_kernel(
    const float* __restrict__ x,
    const float* __restrict__ Wxu, const float* __restrict__ Wxr,
    const float* __restrict__ Wxo,
    const float* __restrict__ bu, const float* __restrict__ br,
    const float* __restrict__ bo,
    unsigned short* __restrict__ Ap)
{
  __shared__ alignas(16) unsigned short x_lds[16 * 256];

  const int tid = threadIdx.x;
  const int w = tid >> 6, l = tid & 63;
  const int q = l >> 4, b16 = l & 15;
  const int bblk = blockIdx.x & 3;
  const int tc = blockIdx.x >> 2;
  const int b0 = bblk * 16;

  short8 wx[6][8];
  f32x4 bbv[6];
#pragma unroll
  for (int n = 0; n < 6; ++n) {
    int ntg = w * 6 + n;
    const float* Wg = (ntg < 16) ? Wxu : (ntg < 32) ? Wxr : Wxo;
    const float* bg = (ntg < 16) ? bu : (ntg < 32) ? br : bo;
    int ct = ntg & 15;
    int col = ct * 16 + b16;
    int c0 = ct * 16 + q * 4;
    bbv[n] = (f32x4){bg[c0], bg[c0 + 1], bg[c0 + 2], bg[c0 + 3]};
#pragma unroll
    for (int kt = 0; kt < 8; ++kt) {
      int k0 = kt * 32 + q * 8;
      short8 f;
#pragma unroll
      for (int j = 0; j < 8; ++j) f[j] = (short)f2bf(Wg[(k0 + j) * 256 + col]);
      wx[n][kt] = f;
    }
  }

  for (int it = 0; it < 8; ++it) {
    const int t = tc * 8 + it;
    {
      int row = tid >> 5;
      int part = tid & 31;
      const float* src = x + (((size_t)(b0 + row) * TT + t) * DD) + part * 8;
      float4 f0 = *(const float4*)(src);
      float4 f1 = *(const float4*)(src + 4);
      us4 s0 = { f2bf(f0.x), f2bf(f0.y), f2bf(f0.z), f2bf(f0.w) };
      us4 s1 = { f2bf(f1.x), f2bf(f1.y), f2bf(f1.z), f2bf(f1.w) };
      unsigned base = swz((unsigned)row, (unsigned)(part * 16));
      *(us4*)((char*)x_lds + base) = s0;
      *(us4*)((char*)x_lds + base + 8) = s1;
    }
    __syncthreads();

    f32x4 acc[6];
#pragma unroll
    for (int n = 0; n < 6; ++n) acc[n] = bbv[n];
#pragma unroll
    for (int kt = 0; kt < 8; ++kt) {
      short8 xa = *(const short8*)((const char*)x_lds + swz(b16, kt * 64 + q * 16));
#pragma unroll
      for (int n = 0; n < 6; ++n) acc[n] = mfma16(wx[n][kt], xa, acc[n]);
    }
    __syncthreads();

#pragma unroll
    for (int n = 0; n < 6; ++n) {
      int ntg = w * 6 + n;
      int g = ntg >> 4, ct = ntg & 15;
      us4 st = { f2bf(acc[n][0]), f2bf(acc[n][1]), f2bf(acc[n][2]), f2bf(acc[n][3]) };
      size_t base = (((size_t)t * 3 + g) * 4 + bblk) * 4096
                    + (ct >> 1) * 512 + l * 8 + (ct & 1) * 4;
      *(us4*)(Ap + base) = st;
    }
  }
}

// ---------------------------------------------------------------------------
// scan_kernel: 4 blocks x 256 threads (4 waves x 64 cols, 1 wave/SIMD).
// LDS map (bytes):
//   ring [0, 98304): 4 slots x {3 gates x 4 waves x 2KB}
//   h    [98304, 107008): 16 rows x 544B  (conflict-free)
//   r    [107008, 115712)
// ---------------------------------------------------------------------------
#define RING_SLOT 24576
#define HOFF 98304
#define ROFF 107008

__global__ __launch_bounds__(256, 1) void scan_kernel(
    const float* __restrict__ Whu, const float* __restrict__ Whr,
    const float* __restrict__ Wro,
    const unsigned short* __restrict__ Ap,
    float* __restrict__ out)
{
  __shared__ alignas(16) char lds8[115712];

  const int tid = threadIdx.x;
  const int w = tid >> 6, l = tid & 63;
  const int q = l >> 4, b16 = l & 15;
  const int bblk = blockIdx.x;
  const int cw = w * 64;                       // wave owns 64 cols

  // --- recurrent weights: 3 gates x 4 n-tiles x 8 kt = 384 dwords -> AGPRs
  short8 wbu[4][8], wbr[4][8], wbo[4][8];
#pragma unroll
  for (int n = 0; n < 4; ++n) {
    const int col = cw + n * 16 + b16;
#pragma unroll
    for (int kt = 0; kt < 8; ++kt) {
      const int k0 = kt * 32 + q * 8;
      short8 fu, fr, fo;
#pragma unroll
      for (int j = 0; j < 8; ++j) {
        fu[j] = (short)f2bf(Whu[(k0 + j) * 256 + col]);
        fr[j] = (short)f2bf(Whr[(k0 + j) * 256 + col]);
        fo[j] = (short)f2bf(Wro[(k0 + j) * 256 + col]);
      }
      wbu[n][kt] = fu; wbr[n][kt] = fr; wbo[n][kt] = fo;
    }
  }

  // --- addresses
  const char* hrd = lds8 + HOFF + b16 * 544 + q * 16;     // + kt*64
  const char* rrd = lds8 + ROFF + b16 * 544 + q * 16;
  char* hwr = lds8 + HOFF + b16 * 544 + (cw + q * 4) * 2; // + n*32
  char* rwr = lds8 + ROFF + b16 * 544 + (cw + q * 4) * 2;
  const char* ringr = lds8 + w * 2048 + l * 16;           // + slot*24576 + g*8192 + c*1024
  const unsigned short* apl = Ap + (size_t)bblk * 4096 + w * 1024 + l * 8;

  // zero h(-1) tile
  for (int i = tid; i < 2176; i += 256) *(int*)(lds8 + HOFF + i * 4) = 0;

  float hm[4][4];
#pragma unroll
  for (int n = 0; n < 4; ++n)
#pragma unroll
    for (int j = 0; j < 4; ++j) hm[n][j] = 0.f;

  // prologue: preload slots 0,1,2 (18 DMA loads in flight)
#pragma unroll
  for (int t0 = 0; t0 < 3; ++t0) {
    const unsigned short* s = apl + (size_t)t0 * 49152u;
    char* d = lds8 + t0 * RING_SLOT + w * 2048;
    load_lds16(s,                d);
    load_lds16(s + 512,          d + 1024);
    load_lds16(s + 16384,        d + 8192);
    load_lds16(s + 16384 + 512,  d + 8192 + 1024);
    load_lds16(s + 32768,        d + 16384);
    load_lds16(s + 32768 + 512,  d + 16384 + 1024);
  }
  __syncthreads();   // h zeros visible (one-time)

#define STEP_BODY(T, SLOT, PSLOT)                                                \
  {                                                                              \
    asm volatile("s_waitcnt vmcnt(12)" ::: "memory");                            \
    { /* prefetch T+3 (clamped; late dups land in dead slots) */                 \
      int tp = (T) + 3; if (tp > TT - 1) tp = TT - 1;                            \
      const unsigned short* s = apl + (size_t)tp * 49152u;                       \
      char* d = lds8 + (PSLOT) * RING_SLOT + w * 2048;                           \
      load_lds16(s,                d);                                           \
      load_lds16(s + 512,          d + 1024);                                    \
      load_lds16(s + 16384,        d + 8192);                                    \
      load_lds16(s + 16384 + 512,  d + 8192 + 1024);                             \
      load_lds16(s + 32768,        d + 16384);                                   \
      load_lds16(s + 32768 + 512,  d + 16384 + 1024);                            \
    }                                                                            \
    const char* rp = ringr + (SLOT) * RING_SLOT;                                 \
    uint4v xu0 = *(const uint4v*)(rp);                                           \
    uint4v xu1 = *(const uint4v*)(rp + 1024);                                    \
    uint4v xr0 = *(const uint4v*)(rp + 8192);                                    \
    uint4v xr1 = *(const uint4v*)(rp + 8192 + 1024);                             \
    uint4v xo0 = *(const uint4v*)(rp + 16384);          /* stash for phase 2 */  \
    uint4v xo1 = *(const uint4v*)(rp + 16384 + 1024);                            \
    f32x4 accu[4], accr[4];                                                      \
    accu[0] = (f32x4){bflo(xu0[0]), bfhi(xu0[0]), bflo(xu0[1]), bfhi(xu0[1])};   \
    accu[1] = (f32x4){bflo(xu0[2]), bfhi(xu0[2]), bflo(xu0[3]), bfhi(xu0[3])};   \
    accu[2] = (f32x4){bflo(xu1[0]), bfhi(xu1[0]), bflo(xu1[1]), bfhi(xu1[1])};   \
    accu[3] = (f32x4){bflo(xu1[2]), bfhi(xu1[2]), bflo(xu1[3]), bfhi(xu1[3])};   \
    accr[0] = (f32x4){bflo(xr0[0]), bfhi(xr0[0]), bflo(xr0[1]), bfhi(xr0[1])};   \
    accr[1] = (f32x4){bflo(xr0[2]), bfhi(xr0[2]), bflo(xr0[3]), bfhi(xr0[3])};   \
    accr[2] = (f32x4){bflo(xr1[0]), bfhi(xr1[0]), bflo(xr1[1]), bfhi(xr1[1])};   \
    accr[3] = (f32x4){bflo(xr1[2]), bfhi(xr1[2]), bflo(xr1[3]), bfhi(xr1[3])};   \
    _Pragma("unroll")                                                            \
    for (int kt = 0; kt < 8; ++kt) {                                             \
      short8 ha = *(const short8*)(hrd + kt * 64);                               \
      accr[0] = mfma16(wbr[0][kt], ha, accr[0]);                                 \
      accr[1] = mfma16(wbr[1][kt], ha, accr[1]);                                 \
      accr[2] = mfma16(wbr[2][kt], ha, accr[2]);                                 \
      accr[3] = mfma16(wbr[3][kt], ha, accr[3]);                                 \
      accu[0] = mfma16(wbu[0][kt], ha, accu[0]);                                 \
      accu[1] = mfma16(wbu[1][kt], ha, accu[1]);                                 \
      accu[2] = mfma16(wbu[2][kt], ha, accu[2]);                                 \
      accu[3] = mfma16(wbu[3][kt], ha, accu[3]);                                 \
    }                                                                            \
    _Pragma("unroll")                                                            \
    for (int n = 0; n < 4; ++n) {                                                \
      float r0 = sigmoid_f(accr[n][0]), r1 = sigmoid_f(accr[n][1]);              \
      float r2 = sigmoid_f(accr[n][2]), r3 = sigmoid_f(accr[n][3]);              \
      *(uint2v*)(rwr + n * 32) = (uint2v){pk2(r0, r1), pk2(r2, r3)};             \
    }                                                                            \
    _Pragma("unroll")                                                            \
    for (int n = 0; n < 4; ++n) {                                                \
      accu[n][0] = sigmoid_f(accu[n][0]); accu[n][1] = sigmoid_f(accu[n][1]);    \
      accu[n][2] = sigmoid_f(accu[n][2]); accu[n][3] = sigmoid_f(accu[n][3]);    \
    }                                                                            \
    asm volatile("s_waitcnt lgkmcnt(0)" ::: "memory");                           \
    __builtin_amdgcn_s_barrier();                                                \
    asm volatile("" ::: "memory");                                               \
    /* ---- phase 2 ---- */                                                      \
    f32x4 acco[4];                                                               \
    acco[0] = (f32x4){bflo(xo0[0]), bfhi(xo0[0]), bflo(xo0[1]), bfhi(xo0[1])};   \
    acco[1] = (f32x4){bflo(xo0[2]), bfhi(xo0[2]), bflo(xo0[3]), bfhi(xo0[3])};   \
    acco[2] = (f32x4){bflo(xo1[0]), bfhi(xo1[0]), bflo(xo1[1]), bfhi(xo1[1])};   \
    acco[3] = (f32x4){bflo(xo1[2]), bfhi(xo1[2]), bflo(xo1[3]), bfhi(xo1[3])};   \
    _Pragma("unroll")                                                            \
    for (int kt = 0; kt < 8; ++kt) {                                             \
      short8 ra = *(const short8*)(rrd + kt * 64);                               \
      acco[0] = mfma16(wbo[0][kt], ra, acco[0]);                                 \
      acco[1] = mfma16(wbo[1][kt], ra, acco[1]);                                 \
      acco[2] = mfma16(wbo[2][kt], ra, acco[2]);                                 \
      acco[3] = mfma16(wbo[3][kt], ra, acco[3]);                                 \
    }                                                                            \
    _Pragma("unroll")                                                            \
    for (int n = 0; n < 4; ++n) {                                                \
      hm[n][0] += accu[n][0] * (tanh_f(acco[n][0]) - hm[n][0]);                  \
      hm[n][1] += accu[n][1] * (tanh_f(acco[n][1]) - hm[n][1]);                  \
      hm[n][2] += accu[n][2] * (tanh_f(acco[n][2]) - hm[n][2]);                  \
      hm[n][3] += accu[n][3] * (tanh_f(acco[n][3]) - hm[n][3]);                  \
      *(uint2v*)(hwr + n * 32) =                                                 \
          (uint2v){pk2(hm[n][0], hm[n][1]), pk2(hm[n][2], hm[n][3])};            \
    }                                                                            \
    asm volatile("s_waitcnt lgkmcnt(0)" ::: "memory");                           \
    __builtin_amdgcn_s_barrier();                                                \
    asm volatile("" ::: "memory");                                               \
  }

  for (int t = 0; t < TT; t += 4) {
    STEP_BODY(t,     0, 3)
    STEP_BODY(t + 1, 1, 0)
    STEP_BODY(t + 2, 2, 1)
    STEP_BODY(t + 3, 3, 2)
  }
#undef STEP_BODY

  const int orow = bblk * 16 + b16;
#pragma unroll
  for (int n = 0; n < 4; ++n)
    *(f32x4*)(&out[orow * 256 + cw + n * 16 + q * 4]) =
        (f32x4){hm[n][0], hm[n][1], hm[n][2], hm[n][3]};
}

__global__ void ws_signal_kernel(float* out, float v) {
  out[blockIdx.x * 256 + threadIdx.x] = v;
}

extern "C" void kernel_launch(void* const* d_in, const int* in_sizes, int n_in,
                              void* d_out, int out_size, void* d_ws, size_t ws_size,
                              hipStream_t stream) {
  const float* x   = (const float*)d_in[0];
  const float* Wxu = (const float*)d_in[1];
  const float* Whu = (const float*)d_in[2];
  const float* bu  = (const float*)d_in[3];
  const float* Wxr = (const float*)d_in[4];
  const float* Whr = (const float*)d_in[5];
  const float* br  = (const float*)d_in[6];
  const float* Wxo = (const float*)d_in[7];
  const float* Wro = (const float*)d_in[8];
  const float* bo  = (const float*)d_in[9];
  float* out = (float*)d_out;

  const size_t needed = (size_t)TT * 3 * 4 * 4096 * 2;  // 192 MiB bf16 A'
  if (ws_size < needed) {
    ws_signal_kernel<<<64, 256, 0, stream>>>(out, (float)(ws_size >> 20));
    return;
  }
  unsigned short* Ap = (unsigned short*)d_ws;
  proj_kernel<<<1024, 512, 0, stream>>>(x, Wxu, Wxr, Wxo, bu, br, bo, Ap);
  scan_kernel<<<4, 256, 0, stream>>>(Whu, Whr, Wro, Ap, out);
}